// Round 4
// baseline (579.266 us; speedup 1.0000x reference)
//
#include <hip/hip_runtime.h>

// ---------------------------------------------------------------------------
// Word_alignment (fp32 I/O):
//   d_in[0] input1 fp32 [8,2048,1024]   d_in[1] input2 fp32 [8,2048,1024]
//   d_in[2] mask   int32 [8,2048]       d_in[3] weight fp32 [1024,1024]
//   d_out  satt    fp32 [8,2048,1024]
// out1 = in1@W^T ; E^T[b,t,s] = mask[b,s] ? exp(<in2[b,t],out1[b,s]>-100) : 0
// l[b,t] = sum_s E^T ; satt[b,t,d] = (1/l) * sum_s E^T[b,t,s]*in1[b,s,d]
//
// R7 -> R8: occupancy, not phase-count. R4-R7 all plateau at ~1060 TF with
// ~2 waves/SIMD (R4: 128^2 multi-block; R5-7: 256^2 1-block/CU) -> exposed
// lgkm windows can't be covered by 1 other wave. New gemm8: 128x256 tile,
// 3-deep BK=32 ring in 72 KiB LDS -> 2 blocks/CU (4 waves/SIMD),
// __launch_bounds__(512,4), acc 4x4 (64 VGPR). Sync minimized to ONE
// barrier + ONE counted vmcnt(3) per K-tile (derivation in gemm8 header).
// Keeps: XOR swizzle (0 conflicts), XCD swizzle, counted vmcnt, NSEG
// K-concatenated hi/lo split, compiler-scheduled lgkm (no forced lgkm(0)).
// Fallback path (R3-proven) untouched.
// ---------------------------------------------------------------------------

typedef short s16x8 __attribute__((ext_vector_type(8)));
typedef float f32x4 __attribute__((ext_vector_type(4)));
typedef unsigned short u16;
typedef unsigned short u16x8 __attribute__((ext_vector_type(8)));

#define B_ 8
#define S1_ 2048
#define S2_ 2048
#define D_ 1024

__device__ __forceinline__ float b2f(u16 u) {
  return __uint_as_float(((unsigned int)u) << 16);
}
__device__ __forceinline__ u16 f2b(float f) {
  unsigned int x = __float_as_uint(f);
  return (u16)((x + 0x7FFFu + ((x >> 16) & 1u)) >> 16);  // RNE
}
__device__ __forceinline__ void gload16(const void* g, void* l) {
  __builtin_amdgcn_global_load_lds(
      (const __attribute__((address_space(1))) unsigned int*)g,
      (__attribute__((address_space(3))) unsigned int*)l, 16, 0, 0);
}

// ============================ FULL PATH ====================================

// fp32 -> bf16 hi + lo (both RNE; residual ~2^-17 relative).
__global__ __launch_bounds__(256) void split_kernel(const float* __restrict__ in,
                                                    u16* __restrict__ hi,
                                                    u16* __restrict__ lo,
                                                    int n4) {
  int i = blockIdx.x * 256 + threadIdx.x;
  if (i >= n4) return;
  f32x4 v = ((const f32x4*)in)[i];
  ushort4 h, l;
  {
    u16 a = f2b(v[0]); h.x = a; l.x = f2b(v[0] - b2f(a));
  }
  {
    u16 a = f2b(v[1]); h.y = a; l.y = f2b(v[1] - b2f(a));
  }
  {
    u16 a = f2b(v[2]); h.z = a; l.z = f2b(v[2] - b2f(a));
  }
  {
    u16 a = f2b(v[3]); h.w = a; l.w = f2b(v[3] - b2f(a));
  }
  ((ushort4*)hi)[i] = h;
  ((ushort4*)lo)[i] = l;
}

// ---------------------------------------------------------------------------
// gemm8: 128x256 tile BT GEMM, C[m,n] = sum_seg sum_k Aseg[m,k]*Bseg[n,k].
// Segments along K (NSEG=3: AhBh + AlBh + AhBl via {Ah,Al,Ah}x{Bh,Bh,Bl}).
// 512 threads = 8 waves (2M x 4N), per-wave 64x64 out, mfma 16x16x32 bf16.
// BK=32; 3-slot LDS ring (slot = A 8KB + B 16KB = 24KB; 72KB total ->
// 2 blocks/CU with __launch_bounds__(512,4); acc 4x4 = 64 VGPR).
// Per K-tile t: { reads(slot t%3): 8 ds_read_b128 ; stage tile t+2 ->
// slot (t+2)%3 (3 global_load_lds) ; 16 MFMA (compiler-interleaved lgkm) ;
// vmcnt(3) ; s_barrier }.
// Sync derivation (1 bar + 1 vmcnt per tile):
//  - reads of tile t are safe: iter t-1 ended with vmcnt(3) retiring ALL of
//    this wave's tile-t loads, followed by the barrier -> every wave passed
//    its own vmcnt before any wave proceeds to iter t.
//  - restage of slot (t+2)%3 (holds tile t-1) is safe: tile t-1's ds_reads
//    drained (lgkm) before their consuming MFMAs in iter t-1, which precede
//    iter t-1's barrier; the stage is issued after that barrier.
// Ledger: entering iter t, outstanding = 3 (tile t+1). Stage -> 6; vmcnt(3)
// retires tile t+1. Tail: iter NT-2 no stage, vmcnt(0); iter NT-1 plain.
// Requires K % 32 == 0, NT >= 3.
// MODE 0: C=(hi,lo) bf16 pair; MODE 1: C=bf16 exp(acc-100)*mask;
// MODE 2: C=fp32 acc*guarded(1/l[m]).
// ---------------------------------------------------------------------------
template <int NSEG, int MODE>
__global__ __launch_bounds__(512, 4) void gemm8(
    const u16* __restrict__ A0, const u16* __restrict__ A1,
    const u16* __restrict__ A2, const u16* __restrict__ B0,
    const u16* __restrict__ B1, const u16* __restrict__ B2,
    void* __restrict__ Cp, u16* __restrict__ C2, int K, int ldc, long sA,
    long sB, long sC, const int* __restrict__ mask, int maskStride,
    const float* __restrict__ lvec, int lvecStride) {
  // 3-slot ring: slot s at u16 offset s*12288; [0,4096) = A tile 128x32,
  // [4096,12288) = B tile 256x32.
  __shared__ __align__(16) u16 S[36864];  // 72 KiB

  // Bijective XCD swizzle on flat block index (total % 8 == 0 for all uses).
  const int gx = gridDim.x, gy = gridDim.y;
  int flat = blockIdx.x + gx * (blockIdx.y + gy * blockIdx.z);
  const int total = gx * gy * (int)gridDim.z;
  const int cpx = total >> 3;
  flat = (flat & 7) * cpx + (flat >> 3);
  const int bx = flat % gx;
  const int rem0 = flat / gx;
  const int by = rem0 % gy;
  const int bz = rem0 / gy;

  const int tid = threadIdx.x;
  const int lane = tid & 63;
  const int wid = tid >> 6;  // 0..7
  const int wr = wid >> 2;   // 0..1 (M, 64 rows each)
  const int wn = wid & 3;    // 0..3 (N, 64 cols each)

  const int tps = K >> 5;  // K-tiles per segment
  const int NT = NSEG * tps;

  // ---- staging geometry. A tile 8KB: thread t covers 16B chunk t
  // (row t>>2 of 128, k-chunk (t&3)^swz). B tile 16KB: chunks t and t+512
  // (rows t>>2 and 128+(t>>2)). Linear LDS dest (wave-uniform base +
  // lane*16B); source k-chunk pre-swizzled: logical = phys ^ ((row>>1)&3).
  const int srow = tid >> 2;  // 0..127
  const int kch = (tid & 3) ^ ((srow >> 1) & 3);
  const long aRow = (long)(by * 128 + srow) * K + kch * 8;
  const long bRow1 = (long)(bx * 256 + srow) * K + kch * 8;
  const long bRow2 = (long)(bx * 256 + srow + 128) * K + kch * 8;

  const u16* aBase0 = A0 + (long)bz * sA;
  const u16* bBase0 = B0 + (long)bz * sB;
  const u16* aBase1 = (NSEG > 1) ? A1 + (long)bz * sA : aBase0;
  const u16* bBase1 = (NSEG > 1) ? B1 + (long)bz * sB : bBase0;
  const u16* aBase2 = (NSEG > 2) ? A2 + (long)bz * sA : aBase0;
  const u16* bBase2 = (NSEG > 2) ? B2 + (long)bz * sB : bBase0;

  // ---- compute-side read addresses (u16 units within a slot).
  // Frag m: row = wr*64 + m*16 + (lane&15); phys chunk = kg ^ ((row>>1)&3)
  // is invariant in m (16-row steps don't change (row>>1)&3).
  const int lr = lane & 15;
  const int kg = lane >> 4;  // 0..3
  const int arow0 = wr * 64 + lr;
  const int aOff = arow0 * 32 + (kg ^ ((arow0 >> 1) & 3)) * 8;
  const int brow0 = wn * 64 + lr;
  const int bOff = 4096 + brow0 * 32 + (kg ^ ((brow0 >> 1) & 3)) * 8;

  const f32x4 z4 = {0.f, 0.f, 0.f, 0.f};
  f32x4 acc[4][4];
#pragma unroll
  for (int i = 0; i < 4; ++i)
#pragma unroll
    for (int j = 0; j < 4; ++j) acc[i][j] = z4;

  // ---- segment cursor (staging walks K' = NSEG*K in tile order).
  int s_rem = 0, s_seg = 0;
  const u16* aS = aBase0;
  const u16* bS = bBase0;

#define STAGE(WOFF_)                                                         \
  {                                                                          \
    gload16(aS + aRow + (long)s_rem * 32, &S[(WOFF_) + tid * 8]);            \
    gload16(bS + bRow1 + (long)s_rem * 32, &S[(WOFF_) + 4096 + tid * 8]);    \
    gload16(bS + bRow2 + (long)s_rem * 32, &S[(WOFF_) + 8192 + tid * 8]);    \
    if (++s_rem == tps) {                                                    \
      s_rem = 0;                                                             \
      ++s_seg;                                                               \
      aS = (s_seg == 1) ? aBase1 : aBase2;                                   \
      bS = (s_seg == 1) ? bBase1 : bBase2;                                   \
    }                                                                        \
  }

  // Prologue: stage tiles 0 -> slot0, 1 -> slot1 (6 loads); tile0 resident.
  STAGE(0)
  STAGE(12288)
  asm volatile("s_waitcnt vmcnt(3)" ::: "memory");
  __builtin_amdgcn_s_barrier();

  int rdOff = 0, wrOff = 24576;

#define KITER(DO_STAGE_, DO_VM3_, DO_VM0_, DO_BAR_)                          \
  {                                                                          \
    asm volatile("" ::: "memory");                                           \
    s16x8 afr[4], bfr[4];                                                    \
    _Pragma("unroll") for (int m_ = 0; m_ < 4; ++m_) afr[m_] =               \
        *(const s16x8*)&S[rdOff + aOff + m_ * 512];                          \
    _Pragma("unroll") for (int n_ = 0; n_ < 4; ++n_) bfr[n_] =               \
        *(const s16x8*)&S[rdOff + bOff + n_ * 512];                          \
    if (DO_STAGE_) STAGE(wrOff)                                              \
    __builtin_amdgcn_s_setprio(1);                                           \
    _Pragma("unroll") for (int m_ = 0; m_ < 4; ++m_)                         \
        _Pragma("unroll") for (int n_ = 0; n_ < 4; ++n_) acc[m_][n_] =       \
            __builtin_amdgcn_mfma_f32_16x16x32_bf16(afr[m_], bfr[n_],        \
                                                    acc[m_][n_], 0, 0, 0);   \
    __builtin_amdgcn_s_setprio(0);                                           \
    if (DO_VM3_) asm volatile("s_waitcnt vmcnt(3)" ::: "memory");            \
    if (DO_VM0_) asm volatile("s_waitcnt vmcnt(0)" ::: "memory");            \
    if (DO_BAR_) {                                                           \
      asm volatile("" ::: "memory");                                         \
      __builtin_amdgcn_s_barrier();                                          \
      asm volatile("" ::: "memory");                                         \
    }                                                                        \
    rdOff += 12288;                                                          \
    if (rdOff == 36864) rdOff = 0;                                           \
    wrOff += 12288;                                                          \
    if (wrOff == 36864) wrOff = 0;                                           \
  }

  for (int t = 0; t < NT - 2; ++t) KITER(true, true, false, true)
  KITER(false, false, true, true)   // t = NT-2: drain tile NT-1
  KITER(false, false, false, false) // t = NT-1: compute only

#undef KITER
#undef STAGE

  // Epilogue. C/D layout: col = lane&15, row = (lane>>4)*4 + reg.
  const int row0 = by * 128 + wr * 64 + kg * 4;
  const int col0 = bx * 256 + wn * 64 + lr;

  if (MODE == 0) {
    u16* Ch = (u16*)Cp;
    u16* Cl = C2;
#pragma unroll
    for (int m = 0; m < 4; ++m)
#pragma unroll
      for (int n = 0; n < 4; ++n)
#pragma unroll
        for (int r = 0; r < 4; ++r) {
          float v = acc[m][n][r];
          long idx = (long)(row0 + m * 16 + r) * ldc + (col0 + n * 16);
          u16 h = f2b(v);
          Ch[idx] = h;
          Cl[idx] = f2b(v - b2f(h));
        }
  } else if (MODE == 1) {
    u16* Cb = (u16*)Cp + (long)bz * sC;
    const int* mb = mask + (long)bz * maskStride;
    int mcol[4];
#pragma unroll
    for (int n = 0; n < 4; ++n) mcol[n] = mb[col0 + n * 16];
#pragma unroll
    for (int m = 0; m < 4; ++m)
#pragma unroll
      for (int n = 0; n < 4; ++n)
#pragma unroll
        for (int r = 0; r < 4; ++r) {
          float v = acc[m][n][r];
          v = mcol[n] ? __expf(v - 100.0f) : 0.0f;
          Cb[(long)(row0 + m * 16 + r) * ldc + (col0 + n * 16)] = f2b(v);
        }
  } else {
    float* Cb = (float*)Cp + (long)bz * sC;
    const float* lb = lvec + (long)bz * lvecStride;
#pragma unroll
    for (int m = 0; m < 4; ++m) {
      float sc[4];
#pragma unroll
      for (int r = 0; r < 4; ++r) {
        float dv = lb[row0 + m * 16 + r];
        sc[r] = (dv > 0.0f) ? 1.0f / dv : 0.0f;
      }
#pragma unroll
      for (int n = 0; n < 4; ++n)
#pragma unroll
        for (int r = 0; r < 4; ++r)
          Cb[(long)(row0 + m * 16 + r) * ldc + (col0 + n * 16)] =
              acc[m][n][r] * sc[r];
    }
  }
}

// ======================= FALLBACK PATH (R3, proven) ========================

__device__ __forceinline__ void split8(const float* __restrict__ g, s16x8& h,
                                       s16x8& l) {
  f32x4 a = *(const f32x4*)g;
  f32x4 b = *(const f32x4*)(g + 4);
#pragma unroll
  for (int j = 0; j < 8; ++j) {
    float x = (j < 4) ? a[j] : b[j - 4];
    u16 hu = f2b(x);
    h[j] = (short)hu;
    l[j] = (short)f2b(x - b2f(hu));
  }
}

template <int MODE>
__global__ __launch_bounds__(256, 2) void gemm_k(
    const void* __restrict__ Ap, const void* __restrict__ Bp,
    const u16* __restrict__ Blo, void* __restrict__ Cp, u16* __restrict__ C2,
    int K, int ldc, long sA, long sB, long sC, const int* __restrict__ mask,
    int maskStride, const float* __restrict__ lvec, int lvecStride) {
  constexpr bool TRI = (MODE != 2);
  __shared__ s16x8 AsH[512];
  __shared__ s16x8 BsH[512];
  __shared__ s16x8 AsL[TRI ? 512 : 1];
  __shared__ s16x8 BsL[TRI ? 512 : 1];

  const int z = blockIdx.z;
  const int tid = threadIdx.x;
  const int lane = tid & 63;
  const int wid = tid >> 6;

  const f32x4 z4 = {0.f, 0.f, 0.f, 0.f};
  f32x4 acc[4][4];
#pragma unroll
  for (int i = 0; i < 4; ++i)
#pragma unroll
    for (int j = 0; j < 4; ++j) acc[i][j] = z4;

  const int wm = (wid & 1) * 64;
  const int wn = (wid >> 1) * 64;
  const int lrow = lane & 15;
  const int kofs = (lane >> 4) * 8;
  const int srow = tid >> 1;
  const int shalf = (tid & 1) * 16;
  const int lidx = (srow * 32 + shalf) >> 3;

  const u16* AsHu = (const u16*)AsH;
  const u16* BsHu = (const u16*)BsH;
  const u16* AsLu = (const u16*)AsL;
  const u16* BsLu = (const u16*)BsL;

  for (int k0 = 0; k0 < K; k0 += 32) {
    if (MODE == 2) {
      const u16* Ab = (const u16*)Ap + z * sA + (long)blockIdx.y * 128 * K;
      const u16* Bb = (const u16*)Bp + z * sB + (long)blockIdx.x * 128 * K;
      const u16* ga = Ab + (long)srow * K + k0 + shalf;
      const u16* gb = Bb + (long)srow * K + k0 + shalf;
      AsH[lidx] = *(const s16x8*)ga;
      AsH[lidx + 1] = *(const s16x8*)(ga + 8);
      BsH[lidx] = *(const s16x8*)gb;
      BsH[lidx + 1] = *(const s16x8*)(gb + 8);
    } else {
      const float* Ab = (const float*)Ap + z * sA + (long)blockIdx.y * 128 * K;
      const float* ga = Ab + (long)srow * K + k0 + shalf;
      split8(ga, AsH[lidx], AsL[lidx]);
      split8(ga + 8, AsH[lidx + 1], AsL[lidx + 1]);
      if (MODE == 0) {
        const float* Bb = (const float*)Bp + z * sB + (long)blockIdx.x * 128 * K;
        const float* gb = Bb + (long)srow * K + k0 + shalf;
        split8(gb, BsH[lidx], BsL[lidx]);
        split8(gb + 8, BsH[lidx + 1], BsL[lidx + 1]);
      } else {
        const u16* Bh = (const u16*)Bp + z * sB + (long)blockIdx.x * 128 * K;
        const u16* Bl = Blo + z * sB + (long)blockIdx.x * 128 * K;
        const u16* gh = Bh + (long)srow * K + k0 + shalf;
        const u16* gl = Bl + (long)srow * K + k0 + shalf;
        BsH[lidx] = *(const s16x8*)gh;
        BsH[lidx + 1] = *(const s16x8*)(gh + 8);
        BsL[lidx] = *(const s16x8*)gl;
        BsL[lidx + 1] = *(const s16x8*)(gl + 8);
      }
    }
    __syncthreads();
    s16x8 ah[4], bh[4], al[4], bl[4];
#pragma unroll
    for (int t = 0; t < 4; ++t) {
      ah[t] = *(const s16x8*)&AsHu[(wm + t * 16 + lrow) * 32 + kofs];
      bh[t] = *(const s16x8*)&BsHu[(wn + t * 16 + lrow) * 32 + kofs];
      if (TRI) {
        al[t] = *(const s16x8*)&AsLu[(wm + t * 16 + lrow) * 32 + kofs];
        bl[t] = *(const s16x8*)&BsLu[(wn + t * 16 + lrow) * 32 + kofs];
      }
    }
#pragma unroll
    for (int i = 0; i < 4; ++i)
#pragma unroll
      for (int j = 0; j < 4; ++j) {
        acc[i][j] = __builtin_amdgcn_mfma_f32_16x16x32_bf16(ah[i], bh[j],
                                                            acc[i][j], 0, 0, 0);
        if (TRI) {
          acc[i][j] = __builtin_amdgcn_mfma_f32_16x16x32_bf16(
              al[i], bh[j], acc[i][j], 0, 0, 0);
          acc[i][j] = __builtin_amdgcn_mfma_f32_16x16x32_bf16(
              ah[i], bl[j], acc[i][j], 0, 0, 0);
        }
      }
    __syncthreads();
  }

  const int row0 = blockIdx.y * 128 + wm + (lane >> 4) * 4;
  const int col0 = blockIdx.x * 128 + wn + lrow;

  if (MODE == 0) {
    u16* Ch = (u16*)Cp;
#pragma unroll
    for (int i = 0; i < 4; ++i)
#pragma unroll
      for (int j = 0; j < 4; ++j)
#pragma unroll
        for (int r = 0; r < 4; ++r) {
          float v = acc[i][j][r];
          long idx = (long)(row0 + i * 16 + r) * ldc + (col0 + j * 16);
          u16 h = f2b(v);
          Ch[idx] = h;
          C2[idx] = f2b(v - b2f(h));
        }
  } else if (MODE == 1) {
    u16* Cb = (u16*)Cp + z * sC;
    const int* mb = mask + (long)z * maskStride;
    int mcol[4];
#pragma unroll
    for (int j = 0; j < 4; ++j) mcol[j] = mb[col0 + j * 16];
#pragma unroll
    for (int i = 0; i < 4; ++i)
#pragma unroll
      for (int j = 0; j < 4; ++j)
#pragma unroll
        for (int r = 0; r < 4; ++r) {
          float v = acc[i][j][r];
          v = mcol[j] ? __expf(v - 100.0f) : 0.0f;
          Cb[(long)(row0 + i * 16 + r) * ldc + (col0 + j * 16)] = f2b(v);
        }
  } else {
    float* Cb = (float*)Cp + z * sC;
    const float* lb = lvec + (long)z * lvecStride;
    float scale[4][4];
#pragma unroll
    for (int i = 0; i < 4; ++i)
#pragma unroll
      for (int r = 0; r < 4; ++r) {
        float dv = lb[row0 + i * 16 + r];
        scale[i][r] = (dv > 0.0f) ? 1.0f / dv : 0.0f;
      }
#pragma unroll
    for (int i = 0; i < 4; ++i)
#pragma unroll
      for (int j = 0; j < 4; ++j)
#pragma unroll
        for (int r = 0; r < 4; ++r)
          Cb[(long)(row0 + i * 16 + r) * ldc + (col0 + j * 16)] =
              acc[i][j][r] * scale[i][r];
  }
}

// ============================ SHARED SMALL KERNELS =========================

__global__ __launch_bounds__(256) void rowsum_kernel(const u16* __restrict__ E,
                                                     float* __restrict__ l) {
  const int row = blockIdx.x * 4 + (threadIdx.x >> 6);
  const int lane = threadIdx.x & 63;
  const u16* p = E + (size_t)row * S1_;
  float s = 0.f;
#pragma unroll
  for (int j = 0; j < 4; ++j) {
    u16x8 v = *(const u16x8*)(p + (j * 64 + lane) * 8);
#pragma unroll
    for (int k = 0; k < 8; ++k) s += b2f(v[k]);
  }
#pragma unroll
  for (int off = 32; off; off >>= 1) s += __shfl_down(s, off, 64);
  if (lane == 0) l[row] = s;
}

__global__ __launch_bounds__(256) void transpose_kernel(
    const float* __restrict__ in, u16* __restrict__ out) {
  __shared__ u16 tile[64][66];
  const int b = blockIdx.z;
  const float* ib = in + (size_t)b * S1_ * D_;
  u16* ob = out + (size_t)b * D_ * S1_;
  const int s0 = blockIdx.x * 64;
  const int d0 = blockIdx.y * 64;
  const int t = threadIdx.x;
  const int tr = t >> 4;
  const int tc = (t & 15) * 4;
#pragma unroll
  for (int i = 0; i < 4; ++i) {
    int row = tr + i * 16;
    f32x4 v = *(const f32x4*)(ib + (size_t)(s0 + row) * D_ + d0 + tc);
    tile[row][tc + 0] = f2b(v[0]);
    tile[row][tc + 1] = f2b(v[1]);
    tile[row][tc + 2] = f2b(v[2]);
    tile[row][tc + 3] = f2b(v[3]);
  }
  __syncthreads();
#pragma unroll
  for (int i = 0; i < 4; ++i) {
    int drow = tr + i * 16;
    ushort4 w;
    w.x = tile[tc + 0][drow];
    w.y = tile[tc + 1][drow];
    w.z = tile[tc + 2][drow];
    w.w = tile[tc + 3][drow];
    *(ushort4*)(ob + (size_t)(d0 + drow) * S1_ + s0 + tc) = w;
  }
}

// ============================ LAUNCH ========================================

extern "C" void kernel_launch(void* const* d_in, const int* in_sizes, int n_in,
                              void* d_out, int out_size, void* d_ws,
                              size_t ws_size, hipStream_t stream) {
  const float* in1 = (const float*)d_in[0];
  const float* in2 = (const float*)d_in[1];
  const int* mask = (const int*)d_in[2];
  const float* W = (const float*)d_in[3];
  float* out = (float*)d_out;
  char* ws = (char*)d_ws;
  const size_t MB = 1024 * 1024;
  dim3 blk(256);
  dim3 blk512(512);

  const size_t FULL_WS = 196 * MB + 64 * 1024;
  if (ws_size >= FULL_WS) {
    // Layout: [0,64) in1_hi/lo -> ET ; [64,128) in2_hi/lo -> in1T(32MB) ;
    // [128,132) W_hi/lo ; [132,196) out1_hi/lo ; [196,+64K) lv.
    u16* in1_hi = (u16*)(ws + 0);
    u16* in1_lo = (u16*)(ws + 32 * MB);
    u16* in2_hi = (u16*)(ws + 64 * MB);
    u16* in2_lo = (u16*)(ws + 96 * MB);
    u16* W_hi = (u16*)(ws + 128 * MB);
    u16* W_lo = (u16*)(ws + 130 * MB);
    u16* out1_hi = (u16*)(ws + 132 * MB);
    u16* out1_lo = (u16*)(ws + 164 * MB);
    float* lv = (float*)(ws + 196 * MB);
    u16* ET = (u16*)(ws + 0);          // after GEMM1 (in1_hi/lo dead)
    u16* in1T = (u16*)(ws + 64 * MB);  // after GEMM2 (in2_hi/lo dead)

    split_kernel<<<dim3(16384), blk, 0, stream>>>(in1, in1_hi, in1_lo,
                                                  B_ * S1_ * D_ / 4);
    split_kernel<<<dim3(16384), blk, 0, stream>>>(in2, in2_hi, in2_lo,
                                                  B_ * S2_ * D_ / 4);
    split_kernel<<<dim3(1024), blk, 0, stream>>>(W, W_hi, W_lo, D_ * D_ / 4);

    // GEMM1: out1 = in1 @ W^T, 3-term (K' = 3*1024), M=16384 N=1024.
    gemm8<3, 0><<<dim3(4, 128, 1), blk512, 0, stream>>>(
        in1_hi, in1_lo, in1_hi, W_hi, W_hi, W_lo, out1_hi, out1_lo, D_, D_, 0,
        0, 0, nullptr, 0, nullptr, 0);

    // GEMM2: E^T = exp(in2 @ out1^T - 100) masked; per batch 2048x2048.
    gemm8<3, 1><<<dim3(8, 16, B_), blk512, 0, stream>>>(
        in2_hi, in2_lo, in2_hi, out1_hi, out1_hi, out1_lo, ET, nullptr, D_,
        S1_, (long)S2_ * D_, (long)S1_ * D_, (long)S2_ * S1_, mask, S1_,
        nullptr, 0);

    rowsum_kernel<<<dim3(B_ * S2_ / 4), blk, 0, stream>>>(ET, lv);
    transpose_kernel<<<dim3(S1_ / 64, D_ / 64, B_), blk, 0, stream>>>(in1, in1T);

    // GEMM3: satt = (E^T @ in1T^T) / l ; per batch 2048x1024 K=2048, 1-term.
    gemm8<1, 2><<<dim3(4, 16, B_), blk512, 0, stream>>>(
        ET, nullptr, nullptr, in1T, nullptr, nullptr, out, nullptr, S1_, D_,
        (long)S2_ * S1_, (long)D_ * S1_, (long)S2_ * D_, nullptr, 0, lv, S2_);
  } else {
    // R3-proven fallback (in-kernel split), 128MB + 64KB.
    u16* out1_hi = (u16*)ws;
    u16* out1_lo = (u16*)(ws + 32 * MB);
    u16* ET = (u16*)(ws + 64 * MB);
    float* lv = (float*)(ws + 128 * MB);
    u16* in1T = out1_hi;

    gemm_k<0><<<dim3(8, 128, 1), blk, 0, stream>>>(
        in1, W, nullptr, out1_hi, out1_lo, D_, D_, 0, 0, 0, nullptr, 0,
        nullptr, 0);
    gemm_k<1><<<dim3(16, 16, B_), blk, 0, stream>>>(
        in2, out1_hi, out1_lo, ET, nullptr, D_, S1_, (long)S2_ * D_,
        (long)S1_ * D_, (long)S2_ * S1_, mask, S1_, nullptr, 0);
    rowsum_kernel<<<dim3(B_ * S2_ / 4), blk, 0, stream>>>(ET, lv);
    transpose_kernel<<<dim3(S1_ / 64, D_ / 64, B_), blk, 0, stream>>>(in1, in1T);
    gemm_k<2><<<dim3(8, 16, B_), blk, 0, stream>>>(
        ET, in1T, nullptr, out, nullptr, S1_, D_, (long)S2_ * S1_,
        (long)D_ * S1_, (long)S2_ * D_, nullptr, 0, lv, S2_);
  }
}

// Round 5
// 450.948 us; speedup vs baseline: 1.2845x; 1.2845x over previous
//
#include <hip/hip_runtime.h>

// ---------------------------------------------------------------------------
// Word_alignment (fp32 I/O):
//   d_in[0] input1 fp32 [8,2048,1024]   d_in[1] input2 fp32 [8,2048,1024]
//   d_in[2] mask   int32 [8,2048]       d_in[3] weight fp32 [1024,1024]
//   d_out  satt    fp32 [8,2048,1024]
// out1 = in1@W^T ; E^T[b,t,s] = mask[b,s] ? exp(<in2[b,t],out1[b,s]>-100) : 0
// l[b,t] = sum_s E^T ; satt[b,t,d] = (1/l) * sum_s E^T[b,t,s]*in1[b,s,d]
//
// R8 -> R9: attack WORK, not schedule. Five schedule variants all plateau at
// 43-50% MfmaUtil (~1060 TF). Switch GEMM1/GEMM2 from bf16 3-term to fp16
// (11-bit mantissa):
//   GEMM1 1-term: in1_h x W_h        (dropped term ~7e-5 abs: W is small)
//   out1 stored fp16 hi+lo pair      (residual ~2^-21 rel)
//   GEMM2 2-term: in2_h x {out1_h, out1_l}  (score err ~0.003 std)
//   GEMM3 unchanged bf16 1-term      (E up to e^20 overflows fp16)
// MFMA work 378 -> 240 GFLOP (-37%). rowsum fused into GEMM2 epilogue
// (shfl-reduce + atomicAdd into lv), removing a pass + 64MB ET re-read.
// gemm8 = R6 structure (best measured GEMM2: 195us) with dtype template.
// Fallback path (R3-proven bf16) untouched.
// ---------------------------------------------------------------------------

typedef short s16x8 __attribute__((ext_vector_type(8)));
typedef float f32x4 __attribute__((ext_vector_type(4)));
typedef unsigned short u16;
typedef unsigned short u16x8 __attribute__((ext_vector_type(8)));
typedef _Float16 f16x8v __attribute__((ext_vector_type(8)));

#define B_ 8
#define S1_ 2048
#define S2_ 2048
#define D_ 1024

__device__ __forceinline__ float b2f(u16 u) {
  return __uint_as_float(((unsigned int)u) << 16);
}
__device__ __forceinline__ u16 f2b(float f) {
  unsigned int x = __float_as_uint(f);
  return (u16)((x + 0x7FFFu + ((x >> 16) & 1u)) >> 16);  // RNE
}
__device__ __forceinline__ u16 f2h(float f) {
  _Float16 h = (_Float16)f;  // v_cvt_f16_f32, RNE
  return __builtin_bit_cast(u16, h);
}
__device__ __forceinline__ float h2f(u16 u) {
  return (float)__builtin_bit_cast(_Float16, u);
}
__device__ __forceinline__ void gload16(const void* g, void* l) {
  __builtin_amdgcn_global_load_lds(
      (const __attribute__((address_space(1))) unsigned int*)g,
      (__attribute__((address_space(3))) unsigned int*)l, 16, 0, 0);
}

template <bool F16>
__device__ __forceinline__ f32x4 mfma16(s16x8 a, s16x8 b, f32x4 c) {
  if constexpr (F16)
    return __builtin_amdgcn_mfma_f32_16x16x32_f16(
        __builtin_bit_cast(f16x8v, a), __builtin_bit_cast(f16x8v, b), c, 0, 0,
        0);
  else
    return __builtin_amdgcn_mfma_f32_16x16x32_bf16(a, b, c, 0, 0, 0);
}

// ============================ FULL PATH ====================================

// fp32 -> fp16 (RNE), vectorized x4.
__global__ __launch_bounds__(256) void split_h_kernel(
    const float* __restrict__ in, u16* __restrict__ h, int n4) {
  int i = blockIdx.x * 256 + threadIdx.x;
  if (i >= n4) return;
  f32x4 v = ((const f32x4*)in)[i];
  ushort4 o;
  o.x = f2h(v[0]);
  o.y = f2h(v[1]);
  o.z = f2h(v[2]);
  o.w = f2h(v[3]);
  ((ushort4*)h)[i] = o;
}

__global__ __launch_bounds__(256) void zero_kernel(float* __restrict__ p,
                                                   int n) {
  int i = blockIdx.x * 256 + threadIdx.x;
  if (i < n) p[i] = 0.f;
}

// ---------------------------------------------------------------------------
// gemm8: 256x256 tile BT GEMM, C[m,n] = sum_seg sum_k Aseg[m,k]*Bseg[n,k].
// K-concatenated segments (NSEG<=3); element dtype = fp16 (F16) or bf16.
// 512 threads = 8 waves (2M x 4N), per-wave 128x64, mfma 16x16x32.
// BK=32; 4-deep LDS ring; R6 iteration shape: per K-tile,
//   reads(12) ; A-stage(t+3) ; bar ; 16 MFMA ; B-stage ; vmcnt(8) ; bar ;
//   16 MFMA.  (proven best of 5 schedule variants: GEMM2 195us)
// Requires NT = NSEG*K/32 with NT%4==0, NT>=8.
// MODE 0: C = fp16 (hi,lo) pair [F16] or bf16 pair; MODE 1: C = bf16
// exp(acc-100)*mask + fused row-sum atomicAdd into lvec; MODE 2: C = fp32
// acc*guarded(1/lvec[m]).
// ---------------------------------------------------------------------------
template <int NSEG, int MODE, bool F16>
__global__ __launch_bounds__(512, 2) void gemm8(
    const u16* __restrict__ A0, const u16* __restrict__ A1,
    const u16* __restrict__ A2, const u16* __restrict__ B0,
    const u16* __restrict__ B1, const u16* __restrict__ B2,
    void* __restrict__ Cp, u16* __restrict__ C2, int K, int ldc, long sA,
    long sB, long sC, const int* __restrict__ mask, int maskStride,
    float* __restrict__ lvec, int lvecStride) {
  // 4-deep ring, distinct arrays so alias analysis stays compile-time exact.
  __shared__ __align__(16) u16 Abuf0[8192];
  __shared__ __align__(16) u16 Abuf1[8192];
  __shared__ __align__(16) u16 Abuf2[8192];
  __shared__ __align__(16) u16 Abuf3[8192];
  __shared__ __align__(16) u16 Bbuf0[8192];
  __shared__ __align__(16) u16 Bbuf1[8192];
  __shared__ __align__(16) u16 Bbuf2[8192];
  __shared__ __align__(16) u16 Bbuf3[8192];

  // Bijective XCD swizzle on flat block index (total % 8 == 0 for all uses).
  const int gx = gridDim.x, gy = gridDim.y;
  int flat = blockIdx.x + gx * (blockIdx.y + gy * blockIdx.z);
  const int total = gx * gy * (int)gridDim.z;
  const int cpx = total >> 3;
  flat = (flat & 7) * cpx + (flat >> 3);
  const int bx = flat % gx;
  const int rem0 = flat / gx;
  const int by = rem0 % gy;
  const int bz = rem0 / gy;

  const int tid = threadIdx.x;
  const int lane = tid & 63;
  const int wid = tid >> 6;  // 0..7
  const int wr = wid >> 2;   // 0..1 (M)
  const int wn = wid & 3;    // 0..3 (N)

  const int tps = K >> 5;  // K-tiles per segment (K pow2)
  const int NT = NSEG * tps;

  // ---- staging geometry: thread t covers 16B chunks t and t+512 of a 16KB
  // tile (rows 0..255 x 64B). Linear LDS dest; source k-chunk pre-swizzled:
  // logical chunk = physical chunk ^ ((row>>1)&3)  (same for row and row+128).
  const int srow = tid >> 2;                    // 0..127
  const int kch = (tid & 3) ^ ((srow >> 1) & 3);
  const long aRow1 = (long)(by * 256 + srow) * K + kch * 8;
  const long aRow2 = (long)(by * 256 + srow + 128) * K + kch * 8;
  const long bRow1 = (long)(bx * 256 + srow) * K + kch * 8;
  const long bRow2 = (long)(bx * 256 + srow + 128) * K + kch * 8;

  const u16* aBase0 = A0 + (long)bz * sA;
  const u16* bBase0 = B0 + (long)bz * sB;
  const u16* aBase1 = (NSEG > 1) ? A1 + (long)bz * sA : aBase0;
  const u16* bBase1 = (NSEG > 1) ? B1 + (long)bz * sB : bBase0;
  const u16* aBase2 = (NSEG > 2) ? A2 + (long)bz * sA : aBase0;
  const u16* bBase2 = (NSEG > 2) ? B2 + (long)bz * sB : bBase0;

  // ---- compute-side read addresses (u16 units within a tile buffer).
  const int lr = lane & 15;
  const int kg = lane >> 4;  // 0..3
  const int arow0 = wr * 128 + lr;
  const int aOffU = arow0 * 32 + (kg ^ ((arow0 >> 1) & 3)) * 8;
  const int brow0 = wn * 64 + lr;
  const int bOffU = brow0 * 32 + (kg ^ ((brow0 >> 1) & 3)) * 8;

  const f32x4 z4 = {0.f, 0.f, 0.f, 0.f};
  f32x4 acc[8][4];
#pragma unroll
  for (int i = 0; i < 8; ++i)
#pragma unroll
    for (int j = 0; j < 4; ++j) acc[i][j] = z4;

  // ---- segment cursor + prologue: stage tiles 0,1,2 (12 loads/thread).
  int s_rem = 0, s_seg = 0;
  const u16* aS = aBase0;
  const u16* bS = bBase0;

#define STAGE_AB(DA_, DB_)                                                   \
  {                                                                          \
    gload16(aS + aRow1 + s_rem * 32, &DA_[wid * 512]);                       \
    gload16(aS + aRow2 + s_rem * 32, &DA_[wid * 512 + 4096]);                \
    gload16(bS + bRow1 + s_rem * 32, &DB_[wid * 512]);                       \
    gload16(bS + bRow2 + s_rem * 32, &DB_[wid * 512 + 4096]);                \
    if (++s_rem == tps) {                                                    \
      s_rem = 0;                                                             \
      ++s_seg;                                                               \
      aS = (s_seg == 1) ? aBase1 : aBase2;                                   \
      bS = (s_seg == 1) ? bBase1 : bBase2;                                   \
    }                                                                        \
  }

  STAGE_AB(Abuf0, Bbuf0);
  STAGE_AB(Abuf1, Bbuf1);
  STAGE_AB(Abuf2, Bbuf2);
  // Tile 0 must be resident before iter-0's (pre-barrier) reads.
  asm volatile("s_waitcnt vmcnt(8)" ::: "memory");
  __builtin_amdgcn_s_barrier();

  // ---- one K-tile iteration (R6 shape).
#define ITER(AS_, BS_, DA_, DB_, VM_, STG_)                                  \
  {                                                                          \
    s16x8 a0[4], a1[4], bfr[4];                                              \
    _Pragma("unroll") for (int m_ = 0; m_ < 4; ++m_) a0[m_] =                \
        *(const s16x8*)&AS_[aOffU + m_ * 512];                               \
    _Pragma("unroll") for (int n_ = 0; n_ < 4; ++n_) bfr[n_] =               \
        *(const s16x8*)&BS_[bOffU + n_ * 512];                               \
    _Pragma("unroll") for (int m_ = 0; m_ < 4; ++m_) a1[m_] =                \
        *(const s16x8*)&AS_[aOffU + (m_ + 4) * 512];                         \
    if (STG_) {                                                              \
      gload16(aS + aRow1 + s_rem * 32, &DA_[wid * 512]);                     \
      gload16(aS + aRow2 + s_rem * 32, &DA_[wid * 512 + 4096]);              \
    }                                                                        \
    asm volatile("" ::: "memory");                                           \
    __builtin_amdgcn_s_barrier();                                            \
    __builtin_amdgcn_sched_barrier(0);                                       \
    __builtin_amdgcn_s_setprio(1);                                           \
    _Pragma("unroll") for (int m_ = 0; m_ < 4; ++m_)                         \
        _Pragma("unroll") for (int n_ = 0; n_ < 4; ++n_) acc[m_][n_] =       \
            mfma16<F16>(a0[m_], bfr[n_], acc[m_][n_]);                       \
    __builtin_amdgcn_s_setprio(0);                                           \
    if (STG_) {                                                              \
      gload16(bS + bRow1 + s_rem * 32, &DB_[wid * 512]);                     \
      gload16(bS + bRow2 + s_rem * 32, &DB_[wid * 512 + 4096]);              \
      if (++s_rem == tps) {                                                  \
        s_rem = 0;                                                           \
        ++s_seg;                                                             \
        aS = (s_seg == 1) ? aBase1 : aBase2;                                 \
        bS = (s_seg == 1) ? bBase1 : bBase2;                                 \
      }                                                                      \
    }                                                                        \
    asm volatile("s_waitcnt " VM_ ::: "memory");                             \
    __builtin_amdgcn_s_barrier();                                            \
    __builtin_amdgcn_sched_barrier(0);                                       \
    __builtin_amdgcn_s_setprio(1);                                           \
    _Pragma("unroll") for (int m_ = 0; m_ < 4; ++m_)                         \
        _Pragma("unroll") for (int n_ = 0; n_ < 4; ++n_) acc[m_ + 4][n_] =   \
            mfma16<F16>(a1[m_], bfr[n_], acc[m_ + 4][n_]);                   \
    __builtin_amdgcn_s_setprio(0);                                           \
  }

  // Main loop unrolled x4 so every LDS buffer reference is a distinct array.
  for (int t = 0; t < NT - 4; t += 4) {
    ITER(Abuf0, Bbuf0, Abuf3, Bbuf3, "vmcnt(8)", true);
    ITER(Abuf1, Bbuf1, Abuf0, Bbuf0, "vmcnt(8)", true);
    ITER(Abuf2, Bbuf2, Abuf1, Bbuf1, "vmcnt(8)", true);
    ITER(Abuf3, Bbuf3, Abuf2, Bbuf2, "vmcnt(8)", true);
  }
  ITER(Abuf0, Bbuf0, Abuf3, Bbuf3, "vmcnt(8)", true);  // stages tile NT-1
  ITER(Abuf1, Bbuf1, Abuf0, Bbuf0, "vmcnt(4)", false);
  ITER(Abuf2, Bbuf2, Abuf1, Bbuf1, "vmcnt(0)", false);
  ITER(Abuf3, Bbuf3, Abuf2, Bbuf2, "vmcnt(0)", false);

#undef ITER
#undef STAGE_AB

  // Epilogue. C/D layout: col = lane&15, row = (lane>>4)*4 + reg.
  const int row0 = by * 256 + wr * 128 + kg * 4;
  const int col0 = bx * 256 + wn * 64 + lr;

  if (MODE == 0) {
    u16* Ch = (u16*)Cp;
    u16* Cl = C2;
#pragma unroll
    for (int m = 0; m < 8; ++m)
#pragma unroll
      for (int n = 0; n < 4; ++n)
#pragma unroll
        for (int r = 0; r < 4; ++r) {
          float v = acc[m][n][r];
          long idx = (long)(row0 + m * 16 + r) * ldc + (col0 + n * 16);
          if (F16) {
            u16 h = f2h(v);
            Ch[idx] = h;
            Cl[idx] = f2h(v - h2f(h));
          } else {
            u16 h = f2b(v);
            Ch[idx] = h;
            Cl[idx] = f2b(v - b2f(h));
          }
        }
  } else if (MODE == 1) {
    u16* Cb = (u16*)Cp + (long)bz * sC;
    const int* mb = mask + (long)bz * maskStride;
    float* lvout = lvec + (long)bz * lvecStride;
    int mcol[4];
#pragma unroll
    for (int n = 0; n < 4; ++n) mcol[n] = mb[col0 + n * 16];
#pragma unroll
    for (int m = 0; m < 8; ++m)
#pragma unroll
      for (int r = 0; r < 4; ++r) {
        float rv = 0.f;
#pragma unroll
        for (int n = 0; n < 4; ++n) {
          float v = acc[m][n][r];
          v = mcol[n] ? __expf(v - 100.0f) : 0.0f;
          Cb[(long)(row0 + m * 16 + r) * ldc + (col0 + n * 16)] = f2b(v);
          rv += v;
        }
        // Row-sum across the 16 lanes of this kg-group (cols lr + n*16).
        rv += __shfl_xor(rv, 1, 16);
        rv += __shfl_xor(rv, 2, 16);
        rv += __shfl_xor(rv, 4, 16);
        rv += __shfl_xor(rv, 8, 16);
        if (lr == 0) atomicAdd(&lvout[row0 + m * 16 + r], rv);
      }
  } else {
    float* Cb = (float*)Cp + (long)bz * sC;
    const float* lb = lvec + (long)bz * lvecStride;
#pragma unroll
    for (int m = 0; m < 8; ++m) {
      float sc[4];
#pragma unroll
      for (int r = 0; r < 4; ++r) {
        float dv = lb[row0 + m * 16 + r];
        sc[r] = (dv > 0.0f) ? 1.0f / dv : 0.0f;
      }
#pragma unroll
      for (int n = 0; n < 4; ++n)
#pragma unroll
        for (int r = 0; r < 4; ++r)
          Cb[(long)(row0 + m * 16 + r) * ldc + (col0 + n * 16)] =
              acc[m][n][r] * sc[r];
    }
  }
}

// ======================= FALLBACK PATH (R3, proven) ========================

__device__ __forceinline__ void split8(const float* __restrict__ g, s16x8& h,
                                       s16x8& l) {
  f32x4 a = *(const f32x4*)g;
  f32x4 b = *(const f32x4*)(g + 4);
#pragma unroll
  for (int j = 0; j < 8; ++j) {
    float x = (j < 4) ? a[j] : b[j - 4];
    u16 hu = f2b(x);
    h[j] = (short)hu;
    l[j] = (short)f2b(x - b2f(hu));
  }
}

template <int MODE>
__global__ __launch_bounds__(256, 2) void gemm_k(
    const void* __restrict__ Ap, const void* __restrict__ Bp,
    const u16* __restrict__ Blo, void* __restrict__ Cp, u16* __restrict__ C2,
    int K, int ldc, long sA, long sB, long sC, const int* __restrict__ mask,
    int maskStride, const float* __restrict__ lvec, int lvecStride) {
  constexpr bool TRI = (MODE != 2);
  __shared__ s16x8 AsH[512];
  __shared__ s16x8 BsH[512];
  __shared__ s16x8 AsL[TRI ? 512 : 1];
  __shared__ s16x8 BsL[TRI ? 512 : 1];

  const int z = blockIdx.z;
  const int tid = threadIdx.x;
  const int lane = tid & 63;
  const int wid = tid >> 6;

  const f32x4 z4 = {0.f, 0.f, 0.f, 0.f};
  f32x4 acc[4][4];
#pragma unroll
  for (int i = 0; i < 4; ++i)
#pragma unroll
    for (int j = 0; j < 4; ++j) acc[i][j] = z4;

  const int wm = (wid & 1) * 64;
  const int wn = (wid >> 1) * 64;
  const int lrow = lane & 15;
  const int kofs = (lane >> 4) * 8;
  const int srow = tid >> 1;
  const int shalf = (tid & 1) * 16;
  const int lidx = (srow * 32 + shalf) >> 3;

  const u16* AsHu = (const u16*)AsH;
  const u16* BsHu = (const u16*)BsH;
  const u16* AsLu = (const u16*)AsL;
  const u16* BsLu = (const u16*)BsL;

  for (int k0 = 0; k0 < K; k0 += 32) {
    if (MODE == 2) {
      const u16* Ab = (const u16*)Ap + z * sA + (long)blockIdx.y * 128 * K;
      const u16* Bb = (const u16*)Bp + z * sB + (long)blockIdx.x * 128 * K;
      const u16* ga = Ab + (long)srow * K + k0 + shalf;
      const u16* gb = Bb + (long)srow * K + k0 + shalf;
      AsH[lidx] = *(const s16x8*)ga;
      AsH[lidx + 1] = *(const s16x8*)(ga + 8);
      BsH[lidx] = *(const s16x8*)gb;
      BsH[lidx + 1] = *(const s16x8*)(gb + 8);
    } else {
      const float* Ab = (const float*)Ap + z * sA + (long)blockIdx.y * 128 * K;
      const float* ga = Ab + (long)srow * K + k0 + shalf;
      split8(ga, AsH[lidx], AsL[lidx]);
      split8(ga + 8, AsH[lidx + 1], AsL[lidx + 1]);
      if (MODE == 0) {
        const float* Bb = (const float*)Bp + z * sB + (long)blockIdx.x * 128 * K;
        const float* gb = Bb + (long)srow * K + k0 + shalf;
        split8(gb, BsH[lidx], BsL[lidx]);
        split8(gb + 8, BsH[lidx + 1], BsL[lidx + 1]);
      } else {
        const u16* Bh = (const u16*)Bp + z * sB + (long)blockIdx.x * 128 * K;
        const u16* Bl = Blo + z * sB + (long)blockIdx.x * 128 * K;
        const u16* gh = Bh + (long)srow * K + k0 + shalf;
        const u16* gl = Bl + (long)srow * K + k0 + shalf;
        BsH[lidx] = *(const s16x8*)gh;
        BsH[lidx + 1] = *(const s16x8*)(gh + 8);
        BsL[lidx] = *(const s16x8*)gl;
        BsL[lidx + 1] = *(const s16x8*)(gl + 8);
      }
    }
    __syncthreads();
    s16x8 ah[4], bh[4], al[4], bl[4];
#pragma unroll
    for (int t = 0; t < 4; ++t) {
      ah[t] = *(const s16x8*)&AsHu[(wm + t * 16 + lrow) * 32 + kofs];
      bh[t] = *(const s16x8*)&BsHu[(wn + t * 16 + lrow) * 32 + kofs];
      if (TRI) {
        al[t] = *(const s16x8*)&AsLu[(wm + t * 16 + lrow) * 32 + kofs];
        bl[t] = *(const s16x8*)&BsLu[(wn + t * 16 + lrow) * 32 + kofs];
      }
    }
#pragma unroll
    for (int i = 0; i < 4; ++i)
#pragma unroll
      for (int j = 0; j < 4; ++j) {
        acc[i][j] = __builtin_amdgcn_mfma_f32_16x16x32_bf16(ah[i], bh[j],
                                                            acc[i][j], 0, 0, 0);
        if (TRI) {
          acc[i][j] = __builtin_amdgcn_mfma_f32_16x16x32_bf16(
              al[i], bh[j], acc[i][j], 0, 0, 0);
          acc[i][j] = __builtin_amdgcn_mfma_f32_16x16x32_bf16(
              ah[i], bl[j], acc[i][j], 0, 0, 0);
        }
      }
    __syncthreads();
  }

  const int row0 = blockIdx.y * 128 + wm + (lane >> 4) * 4;
  const int col0 = blockIdx.x * 128 + wn + lrow;

  if (MODE == 0) {
    u16* Ch = (u16*)Cp;
#pragma unroll
    for (int i = 0; i < 4; ++i)
#pragma unroll
      for (int j = 0; j < 4; ++j)
#pragma unroll
        for (int r = 0; r < 4; ++r) {
          float v = acc[i][j][r];
          long idx = (long)(row0 + i * 16 + r) * ldc + (col0 + j * 16);
          u16 h = f2b(v);
          Ch[idx] = h;
          C2[idx] = f2b(v - b2f(h));
        }
  } else if (MODE == 1) {
    u16* Cb = (u16*)Cp + z * sC;
    const int* mb = mask + (long)z * maskStride;
    int mcol[4];
#pragma unroll
    for (int j = 0; j < 4; ++j) mcol[j] = mb[col0 + j * 16];
#pragma unroll
    for (int i = 0; i < 4; ++i)
#pragma unroll
      for (int j = 0; j < 4; ++j)
#pragma unroll
        for (int r = 0; r < 4; ++r) {
          float v = acc[i][j][r];
          v = mcol[j] ? __expf(v - 100.0f) : 0.0f;
          Cb[(long)(row0 + i * 16 + r) * ldc + (col0 + j * 16)] = f2b(v);
        }
  } else {
    float* Cb = (float*)Cp + z * sC;
    const float* lb = lvec + (long)z * lvecStride;
    float scale[4][4];
#pragma unroll
    for (int i = 0; i < 4; ++i)
#pragma unroll
      for (int r = 0; r < 4; ++r) {
        float dv = lb[row0 + i * 16 + r];
        scale[i][r] = (dv > 0.0f) ? 1.0f / dv : 0.0f;
      }
#pragma unroll
    for (int i = 0; i < 4; ++i)
#pragma unroll
      for (int j = 0; j < 4; ++j)
#pragma unroll
        for (int r = 0; r < 4; ++r)
          Cb[(long)(row0 + i * 16 + r) * ldc + (col0 + j * 16)] =
              acc[i][j][r] * scale[i][r];
  }
}

// ============================ SHARED SMALL KERNELS =========================

__global__ __launch_bounds__(256) void rowsum_kernel(const u16* __restrict__ E,
                                                     float* __restrict__ l) {
  const int row = blockIdx.x * 4 + (threadIdx.x >> 6);
  const int lane = threadIdx.x & 63;
  const u16* p = E + (size_t)row * S1_;
  float s = 0.f;
#pragma unroll
  for (int j = 0; j < 4; ++j) {
    u16x8 v = *(const u16x8*)(p + (j * 64 + lane) * 8);
#pragma unroll
    for (int k = 0; k < 8; ++k) s += b2f(v[k]);
  }
#pragma unroll
  for (int off = 32; off; off >>= 1) s += __shfl_down(s, off, 64);
  if (lane == 0) l[row] = s;
}

__global__ __launch_bounds__(256) void transpose_kernel(
    const float* __restrict__ in, u16* __restrict__ out) {
  __shared__ u16 tile[64][66];
  const int b = blockIdx.z;
  const float* ib = in + (size_t)b * S1_ * D_;
  u16* ob = out + (size_t)b * D_ * S1_;
  const int s0 = blockIdx.x * 64;
  const int d0 = blockIdx.y * 64;
  const int t = threadIdx.x;
  const int tr = t >> 4;
  const int tc = (t & 15) * 4;
#pragma unroll
  for (int i = 0; i < 4; ++i) {
    int row = tr + i * 16;
    f32x4 v = *(const f32x4*)(ib + (size_t)(s0 + row) * D_ + d0 + tc);
    tile[row][tc + 0] = f2b(v[0]);
    tile[row][tc + 1] = f2b(v[1]);
    tile[row][tc + 2] = f2b(v[2]);
    tile[row][tc + 3] = f2b(v[3]);
  }
  __syncthreads();
#pragma unroll
  for (int i = 0; i < 4; ++i) {
    int drow = tr + i * 16;
    ushort4 w;
    w.x = tile[tc + 0][drow];
    w.y = tile[tc + 1][drow];
    w.z = tile[tc + 2][drow];
    w.w = tile[tc + 3][drow];
    *(ushort4*)(ob + (size_t)(d0 + drow) * S1_ + s0 + tc) = w;
  }
}

// ============================ LAUNCH ========================================

extern "C" void kernel_launch(void* const* d_in, const int* in_sizes, int n_in,
                              void* d_out, int out_size, void* d_ws,
                              size_t ws_size, hipStream_t stream) {
  const float* in1 = (const float*)d_in[0];
  const float* in2 = (const float*)d_in[1];
  const int* mask = (const int*)d_in[2];
  const float* W = (const float*)d_in[3];
  float* out = (float*)d_out;
  char* ws = (char*)d_ws;
  const size_t MB = 1024 * 1024;
  dim3 blk(256);
  dim3 blk512(512);

  const size_t FULL_WS = 196 * MB + 64 * 1024;
  if (ws_size >= FULL_WS) {
    // Layout (fp16 path): [0,32) in1_h -> in1T(bf16) after GEMM1 ;
    // [32,64) in2_h ; [64,66) W_h ; [66,130) ET (bf16) ;
    // [130,162) out1_h ; [162,194) out1_l ; [194,+64K) lv.
    u16* in1_h = (u16*)(ws + 0);
    u16* in2_h = (u16*)(ws + 32 * MB);
    u16* W_h = (u16*)(ws + 64 * MB);
    u16* ET = (u16*)(ws + 66 * MB);
    u16* out1_h = (u16*)(ws + 130 * MB);
    u16* out1_l = (u16*)(ws + 162 * MB);
    float* lv = (float*)(ws + 194 * MB);
    u16* in1T = (u16*)(ws + 0);  // reuse in1_h region after GEMM1

    split_h_kernel<<<dim3(16384), blk, 0, stream>>>(in1, in1_h,
                                                    B_ * S1_ * D_ / 4);
    split_h_kernel<<<dim3(16384), blk, 0, stream>>>(in2, in2_h,
                                                    B_ * S2_ * D_ / 4);
    split_h_kernel<<<dim3(1024), blk, 0, stream>>>(W, W_h, D_ * D_ / 4);
    zero_kernel<<<dim3(64), blk, 0, stream>>>(lv, B_ * S2_);

    // GEMM1: out1 = in1 @ W^T, fp16 1-term, M=16384 N=1024 K=1024; output
    // stored as fp16 hi+lo pair.
    gemm8<1, 0, true><<<dim3(4, 64, 1), blk512, 0, stream>>>(
        in1_h, in1_h, in1_h, W_h, W_h, W_h, out1_h, out1_l, D_, D_, 0, 0, 0,
        nullptr, 0, nullptr, 0);

    // GEMM2: E^T = exp(in2 @ out1^T - 100) masked, fp16 2-term
    // (B segments {out1_h, out1_l}); fused row-sum into lv.
    gemm8<2, 1, true><<<dim3(8, 8, B_), blk512, 0, stream>>>(
        in2_h, in2_h, in2_h, out1_h, out1_l, out1_l, ET, nullptr, D_, S1_,
        (long)S2_ * D_, (long)S1_ * D_, (long)S2_ * S1_, mask, S1_, lv, S2_);

    transpose_kernel<<<dim3(S1_ / 64, D_ / 64, B_), blk, 0, stream>>>(in1, in1T);

    // GEMM3: satt = (E^T @ in1T^T) / l ; bf16 1-term, per batch 2048x1024
    // K=2048.
    gemm8<1, 2, false><<<dim3(4, 8, B_), blk512, 0, stream>>>(
        ET, ET, ET, in1T, in1T, in1T, out, nullptr, S1_, D_, (long)S2_ * S1_,
        (long)D_ * S1_, (long)S2_ * D_, nullptr, 0, lv, S2_);
  } else {
    // R3-proven fallback (in-kernel split), 128MB + 64KB.
    u16* out1_hi = (u16*)ws;
    u16* out1_lo = (u16*)(ws + 32 * MB);
    u16* ET = (u16*)(ws + 64 * MB);
    float* lv = (float*)(ws + 128 * MB);
    u16* in1T = out1_hi;

    gemm_k<0><<<dim3(8, 128, 1), blk, 0, stream>>>(
        in1, W, nullptr, out1_hi, out1_lo, D_, D_, 0, 0, 0, nullptr, 0,
        nullptr, 0);
    gemm_k<1><<<dim3(16, 16, B_), blk, 0, stream>>>(
        in2, out1_hi, out1_lo, ET, nullptr, D_, S1_, (long)S2_ * D_,
        (long)S1_ * D_, (long)S2_ * S1_, mask, S1_, nullptr, 0);
    rowsum_kernel<<<dim3(B_ * S2_ / 4), blk, 0, stream>>>(ET, lv);
    transpose_kernel<<<dim3(S1_ / 64, D_ / 64, B_), blk, 0, stream>>>(in1, in1T);
    gemm_k<2><<<dim3(8, 16, B_), blk, 0, stream>>>(
        ET, in1T, nullptr, out, nullptr, S1_, D_, (long)S2_ * S1_,
        (long)D_ * S1_, (long)S2_ * D_, nullptr, 0, lv, S2_);
  }
}

// Round 6
// 390.445 us; speedup vs baseline: 1.4836x; 1.1550x over previous
//
#include <hip/hip_runtime.h>

// ---------------------------------------------------------------------------
// Word_alignment (fp32 I/O):
//   d_in[0] input1 fp32 [8,2048,1024]   d_in[1] input2 fp32 [8,2048,1024]
//   d_in[2] mask   int32 [8,2048]       d_in[3] weight fp32 [1024,1024]
//   d_out  satt    fp32 [8,2048,1024]
// out1 = in1@W^T ; E^T[b,t,s] = mask[b,s] ? exp(<in2[b,t],out1[b,s]>-100) : 0
// l[b,t] = sum_s E^T ; satt[b,t,d] = (1/l) * sum_s E^T[b,t,s]*in1[b,s,d]
//
// R9 -> R10: mask compaction. ~50% of s-rows are masked -> E^T columns are
// exactly 0 -> skip them everywhere. Device-side compact (sidx/cnt/kr per
// batch; kr = round128(cnt), min 256); host grids stay worst-case, blocks
// early-exit on kr[b] (no host sync under graph capture).
//   GEMM1: computes out1 COMPACTED (A-row indirection via sidx; early-exit
//          by*256>=kr) -> ~40us
//   GEMM2: B = compact out1 (no indirection); early-exit bx*256>=kr; valid
//          col = col<cnt (replaces mask) -> ~105us
//   GEMM3: K = kr[b] (runtime per batch); ET and in1TC zero on [cnt,kr)
//          -> ~100us
// Numerics unchanged vs R9 (masked contributions were already exactly 0).
// gemm8 keeps the R6/R9 proven pipeline (256^2, 4-deep ring, counted
// vmcnt(8), XOR swizzle, fp16 GEMM1/2, fused rowsum). Fallback untouched.
// ---------------------------------------------------------------------------

typedef short s16x8 __attribute__((ext_vector_type(8)));
typedef float f32x4 __attribute__((ext_vector_type(4)));
typedef unsigned short u16;
typedef unsigned short u16x8 __attribute__((ext_vector_type(8)));
typedef _Float16 f16x8v __attribute__((ext_vector_type(8)));

#define B_ 8
#define S1_ 2048
#define S2_ 2048
#define D_ 1024

__device__ __forceinline__ float b2f(u16 u) {
  return __uint_as_float(((unsigned int)u) << 16);
}
__device__ __forceinline__ u16 f2b(float f) {
  unsigned int x = __float_as_uint(f);
  return (u16)((x + 0x7FFFu + ((x >> 16) & 1u)) >> 16);  // RNE
}
__device__ __forceinline__ u16 f2h(float f) {
  _Float16 h = (_Float16)f;  // v_cvt_f16_f32, RNE
  return __builtin_bit_cast(u16, h);
}
__device__ __forceinline__ float h2f(u16 u) {
  return (float)__builtin_bit_cast(_Float16, u);
}
__device__ __forceinline__ void gload16(const void* g, void* l) {
  __builtin_amdgcn_global_load_lds(
      (const __attribute__((address_space(1))) unsigned int*)g,
      (__attribute__((address_space(3))) unsigned int*)l, 16, 0, 0);
}

template <bool F16>
__device__ __forceinline__ f32x4 mfma16(s16x8 a, s16x8 b, f32x4 c) {
  if constexpr (F16)
    return __builtin_amdgcn_mfma_f32_16x16x32_f16(
        __builtin_bit_cast(f16x8v, a), __builtin_bit_cast(f16x8v, b), c, 0, 0,
        0);
  else
    return __builtin_amdgcn_mfma_f32_16x16x32_bf16(a, b, c, 0, 0, 0);
}

// ============================ FULL PATH ====================================

// fp32 -> fp16 (RNE), vectorized x4.
__global__ __launch_bounds__(256) void split_h_kernel(
    const float* __restrict__ in, u16* __restrict__ h, int n4) {
  int i = blockIdx.x * 256 + threadIdx.x;
  if (i >= n4) return;
  f32x4 v = ((const f32x4*)in)[i];
  ushort4 o;
  o.x = f2h(v[0]);
  o.y = f2h(v[1]);
  o.z = f2h(v[2]);
  o.w = f2h(v[3]);
  ((ushort4*)h)[i] = o;
}

__global__ __launch_bounds__(256) void zero_kernel(float* __restrict__ p,
                                                   int n) {
  int i = blockIdx.x * 256 + threadIdx.x;
  if (i < n) p[i] = 0.f;
}

// Per-batch order-preserving compaction of active s indices.
// sidx must be pre-zeroed (pad entries -> row 0, finite data, selected away).
__global__ __launch_bounds__(256) void compact_kernel(
    const int* __restrict__ mask, int* __restrict__ sidx,
    int* __restrict__ cnt, int* __restrict__ kr) {
  const int b = blockIdx.x;
  const int* mb = mask + (long)b * S1_;
  int* sb = sidx + (long)b * S1_;
  const int t = threadIdx.x;
  const int lane = t & 63, w = t >> 6;
  __shared__ int wsum[4];
  int loc[8], c = 0;
#pragma unroll
  for (int j = 0; j < 8; ++j) {
    loc[j] = (mb[t * 8 + j] != 0);
    c += loc[j];
  }
  int inc = c;  // inclusive scan within wave
  for (int off = 1; off < 64; off <<= 1) {
    int v = __shfl_up(inc, off, 64);
    if (lane >= off) inc += v;
  }
  if (lane == 63) wsum[w] = inc;
  __syncthreads();
  int woff = 0;
#pragma unroll
  for (int i = 0; i < 4; ++i)
    if (i < w) woff += wsum[i];
  int pos = woff + inc - c;  // exclusive prefix
#pragma unroll
  for (int j = 0; j < 8; ++j)
    if (loc[j]) sb[pos++] = t * 8 + j;
  if (t == 255) {
    int tot = woff + inc;
    cnt[b] = tot;
    int r = (tot + 127) & ~127;
    if (r < 256) r = 256;
    kr[b] = r;
  }
}

// ---------------------------------------------------------------------------
// gemm8: 256x256 tile BT GEMM, C[m,n] = sum_seg sum_k Aseg[m,k]*Bseg[n,k].
// K-concatenated segments (NSEG<=3); dtype fp16 (F16) or bf16.
// 512 threads = 8 waves (2M x 4N), per-wave 128x64, mfma 16x16x32.
// BK=32; 4-deep LDS ring; R6 iteration shape (proven best):
//   reads(12) ; A-stage(t+3) ; bar ; 16 MFMA ; B-stage ; vmcnt(8) ; bar ;
//   16 MFMA.
// INDA: A global rows indirected via sidx[bz][row] (GEMM1 compaction);
//       early-exit when by*256 >= kr[bz].
// DYNK: K extent = kr[bz] at runtime (row strides stay lda/ldb).
// MODE 0: C = (hi,lo) pair at bz*sC; MODE 1: C = bf16 exp(acc-100) for
// cols < cnt[bz] else 0, + fused row-sum atomicAdd into lvec; early-exit
// when bx*256 >= kr[bz]. MODE 2: C = fp32 acc*guarded(1/lvec[m]).
// Requires NT = NSEG*Keff/32 with NT%4==0, NT>=8 (Keff mult of 128, >=256).
// ---------------------------------------------------------------------------
template <int NSEG, int MODE, bool F16, bool INDA, bool DYNK>
__global__ __launch_bounds__(512, 2) void gemm8(
    const u16* __restrict__ A0, const u16* __restrict__ A1,
    const u16* __restrict__ A2, const u16* __restrict__ B0,
    const u16* __restrict__ B1, const u16* __restrict__ B2,
    void* __restrict__ Cp, u16* __restrict__ C2, int K, int lda, int ldb,
    int ldc, long sA, long sB, long sC, const int* __restrict__ sidx,
    int sidxStride, const int* __restrict__ cntArr,
    const int* __restrict__ krArr, float* __restrict__ lvec, int lvecStride) {
  // 4-deep ring, distinct arrays so alias analysis stays compile-time exact.
  __shared__ __align__(16) u16 Abuf0[8192];
  __shared__ __align__(16) u16 Abuf1[8192];
  __shared__ __align__(16) u16 Abuf2[8192];
  __shared__ __align__(16) u16 Abuf3[8192];
  __shared__ __align__(16) u16 Bbuf0[8192];
  __shared__ __align__(16) u16 Bbuf1[8192];
  __shared__ __align__(16) u16 Bbuf2[8192];
  __shared__ __align__(16) u16 Bbuf3[8192];

  // Bijective XCD swizzle on flat block index (total % 8 == 0 for all uses).
  const int gx = gridDim.x, gy = gridDim.y;
  int flat = blockIdx.x + gx * (blockIdx.y + gy * blockIdx.z);
  const int total = gx * gy * (int)gridDim.z;
  const int cpx = total >> 3;
  flat = (flat & 7) * cpx + (flat >> 3);
  const int bx = flat % gx;
  const int rem0 = flat / gx;
  const int by = rem0 % gy;
  const int bz = rem0 / gy;

  // Compaction early-exits (uniform per block, before any barrier).
  if constexpr (INDA) {
    if (by * 256 >= krArr[bz]) return;
  }
  if constexpr (MODE == 1) {
    if (bx * 256 >= krArr[bz]) return;
  }

  const int tid = threadIdx.x;
  const int lane = tid & 63;
  const int wid = tid >> 6;  // 0..7
  const int wr = wid >> 2;   // 0..1 (M)
  const int wn = wid & 3;    // 0..3 (N)

  const int Keff = DYNK ? krArr[bz] : K;
  const int tps = Keff >> 5;  // K-tiles per segment
  const int NT = NSEG * tps;

  // ---- staging geometry: thread t covers 16B chunks t and t+512 of a 16KB
  // tile (rows 0..255 x 64B). Linear LDS dest; source k-chunk pre-swizzled:
  // logical chunk = physical chunk ^ ((row>>1)&3)  (same for row and row+128).
  const int srow = tid >> 2;  // 0..127
  const int kch = (tid & 3) ^ ((srow >> 1) & 3);
  int ar0g = by * 256 + srow, ar1g = ar0g + 128;
  if constexpr (INDA) {
    const int* sx = sidx + (long)bz * sidxStride;
    ar0g = sx[ar0g];
    ar1g = sx[ar1g];
  }
  const long aRow1 = (long)ar0g * lda + kch * 8;
  const long aRow2 = (long)ar1g * lda + kch * 8;
  const long bRow1 = (long)(bx * 256 + srow) * ldb + kch * 8;
  const long bRow2 = (long)(bx * 256 + srow + 128) * ldb + kch * 8;

  const u16* aBase0 = A0 + (long)bz * sA;
  const u16* bBase0 = B0 + (long)bz * sB;
  const u16* aBase1 = (NSEG > 1) ? A1 + (long)bz * sA : aBase0;
  const u16* bBase1 = (NSEG > 1) ? B1 + (long)bz * sB : bBase0;
  const u16* aBase2 = (NSEG > 2) ? A2 + (long)bz * sA : aBase0;
  const u16* bBase2 = (NSEG > 2) ? B2 + (long)bz * sB : bBase0;

  // ---- compute-side read addresses (u16 units within a tile buffer).
  const int lr = lane & 15;
  const int kg = lane >> 4;  // 0..3
  const int arow0 = wr * 128 + lr;
  const int aOffU = arow0 * 32 + (kg ^ ((arow0 >> 1) & 3)) * 8;
  const int brow0 = wn * 64 + lr;
  const int bOffU = brow0 * 32 + (kg ^ ((brow0 >> 1) & 3)) * 8;

  const f32x4 z4 = {0.f, 0.f, 0.f, 0.f};
  f32x4 acc[8][4];
#pragma unroll
  for (int i = 0; i < 8; ++i)
#pragma unroll
    for (int j = 0; j < 4; ++j) acc[i][j] = z4;

  // ---- segment cursor + prologue: stage tiles 0,1,2 (12 loads/thread).
  int s_rem = 0, s_seg = 0;
  const u16* aS = aBase0;
  const u16* bS = bBase0;

#define STAGE_AB(DA_, DB_)                                                   \
  {                                                                          \
    gload16(aS + aRow1 + s_rem * 32, &DA_[wid * 512]);                       \
    gload16(aS + aRow2 + s_rem * 32, &DA_[wid * 512 + 4096]);                \
    gload16(bS + bRow1 + s_rem * 32, &DB_[wid * 512]);                       \
    gload16(bS + bRow2 + s_rem * 32, &DB_[wid * 512 + 4096]);                \
    if (++s_rem == tps) {                                                    \
      s_rem = 0;                                                             \
      ++s_seg;                                                               \
      aS = (s_seg == 1) ? aBase1 : aBase2;                                   \
      bS = (s_seg == 1) ? bBase1 : bBase2;                                   \
    }                                                                        \
  }

  STAGE_AB(Abuf0, Bbuf0);
  STAGE_AB(Abuf1, Bbuf1);
  STAGE_AB(Abuf2, Bbuf2);
  // Tile 0 must be resident before iter-0's (pre-barrier) reads.
  asm volatile("s_waitcnt vmcnt(8)" ::: "memory");
  __builtin_amdgcn_s_barrier();

  // ---- one K-tile iteration (R6 shape).
#define ITER(AS_, BS_, DA_, DB_, VM_, STG_)                                  \
  {                                                                          \
    s16x8 a0[4], a1[4], bfr[4];                                              \
    _Pragma("unroll") for (int m_ = 0; m_ < 4; ++m_) a0[m_] =                \
        *(const s16x8*)&AS_[aOffU + m_ * 512];                               \
    _Pragma("unroll") for (int n_ = 0; n_ < 4; ++n_) bfr[n_] =               \
        *(const s16x8*)&BS_[bOffU + n_ * 512];                               \
    _Pragma("unroll") for (int m_ = 0; m_ < 4; ++m_) a1[m_] =                \
        *(const s16x8*)&AS_[aOffU + (m_ + 4) * 512];                         \
    if (STG_) {                                                              \
      gload16(aS + aRow1 + s_rem * 32, &DA_[wid * 512]);                     \
      gload16(aS + aRow2 + s_rem * 32, &DA_[wid * 512 + 4096]);              \
    }                                                                        \
    asm volatile("" ::: "memory");                                           \
    __builtin_amdgcn_s_barrier();                                            \
    __builtin_amdgcn_sched_barrier(0);                                       \
    __builtin_amdgcn_s_setprio(1);                                           \
    _Pragma("unroll") for (int m_ = 0; m_ < 4; ++m_)                         \
        _Pragma("unroll") for (int n_ = 0; n_ < 4; ++n_) acc[m_][n_] =       \
            mfma16<F16>(a0[m_], bfr[n_], acc[m_][n_]);                       \
    __builtin_amdgcn_s_setprio(0);                                           \
    if (STG_) {                                                              \
      gload16(bS + bRow1 + s_rem * 32, &DB_[wid * 512]);                     \
      gload16(bS + bRow2 + s_rem * 32, &DB_[wid * 512 + 4096]);              \
      if (++s_rem == tps) {                                                  \
        s_rem = 0;                                                           \
        ++s_seg;                                                             \
        aS = (s_seg == 1) ? aBase1 : aBase2;                                 \
        bS = (s_seg == 1) ? bBase1 : bBase2;                                 \
      }                                                                      \
    }                                                                        \
    asm volatile("s_waitcnt " VM_ ::: "memory");                             \
    __builtin_amdgcn_s_barrier();                                            \
    __builtin_amdgcn_sched_barrier(0);                                       \
    __builtin_amdgcn_s_setprio(1);                                           \
    _Pragma("unroll") for (int m_ = 0; m_ < 4; ++m_)                         \
        _Pragma("unroll") for (int n_ = 0; n_ < 4; ++n_) acc[m_ + 4][n_] =   \
            mfma16<F16>(a1[m_], bfr[n_], acc[m_ + 4][n_]);                   \
    __builtin_amdgcn_s_setprio(0);                                           \
  }

  // Main loop unrolled x4 so every LDS buffer reference is a distinct array.
  for (int t = 0; t < NT - 4; t += 4) {
    ITER(Abuf0, Bbuf0, Abuf3, Bbuf3, "vmcnt(8)", true);
    ITER(Abuf1, Bbuf1, Abuf0, Bbuf0, "vmcnt(8)", true);
    ITER(Abuf2, Bbuf2, Abuf1, Bbuf1, "vmcnt(8)", true);
    ITER(Abuf3, Bbuf3, Abuf2, Bbuf2, "vmcnt(8)", true);
  }
  ITER(Abuf0, Bbuf0, Abuf3, Bbuf3, "vmcnt(8)", true);  // stages tile NT-1
  ITER(Abuf1, Bbuf1, Abuf0, Bbuf0, "vmcnt(4)", false);
  ITER(Abuf2, Bbuf2, Abuf1, Bbuf1, "vmcnt(0)", false);
  ITER(Abuf3, Bbuf3, Abuf2, Bbuf2, "vmcnt(0)", false);

#undef ITER
#undef STAGE_AB

  // Epilogue. C/D layout: col = lane&15, row = (lane>>4)*4 + reg.
  const int row0 = by * 256 + wr * 128 + kg * 4;
  const int col0 = bx * 256 + wn * 64 + lr;

  if (MODE == 0) {
    u16* Ch = (u16*)Cp + (long)bz * sC;
    u16* Cl = C2 + (long)bz * sC;
#pragma unroll
    for (int m = 0; m < 8; ++m)
#pragma unroll
      for (int n = 0; n < 4; ++n)
#pragma unroll
        for (int r = 0; r < 4; ++r) {
          float v = acc[m][n][r];
          long idx = (long)(row0 + m * 16 + r) * ldc + (col0 + n * 16);
          if (F16) {
            u16 h = f2h(v);
            Ch[idx] = h;
            Cl[idx] = f2h(v - h2f(h));
          } else {
            u16 h = f2b(v);
            Ch[idx] = h;
            Cl[idx] = f2b(v - b2f(h));
          }
        }
  } else if (MODE == 1) {
    u16* Cb = (u16*)Cp + (long)bz * sC;
    float* lvout = lvec + (long)bz * lvecStride;
    const int cn = cntArr[bz];
    int mcol[4];
#pragma unroll
    for (int n = 0; n < 4; ++n) mcol[n] = (col0 + n * 16) < cn;
#pragma unroll
    for (int m = 0; m < 8; ++m)
#pragma unroll
      for (int r = 0; r < 4; ++r) {
        float rv = 0.f;
#pragma unroll
        for (int n = 0; n < 4; ++n) {
          float v = acc[m][n][r];
          v = mcol[n] ? __expf(v - 100.0f) : 0.0f;
          Cb[(long)(row0 + m * 16 + r) * ldc + (col0 + n * 16)] = f2b(v);
          rv += v;
        }
        // Row-sum across the 16 lanes of this kg-group (cols lr + n*16).
        rv += __shfl_xor(rv, 1, 16);
        rv += __shfl_xor(rv, 2, 16);
        rv += __shfl_xor(rv, 4, 16);
        rv += __shfl_xor(rv, 8, 16);
        if (lr == 0) atomicAdd(&lvout[row0 + m * 16 + r], rv);
      }
  } else {
    float* Cb = (float*)Cp + (long)bz * sC;
    const float* lb = lvec + (long)bz * lvecStride;
#pragma unroll
    for (int m = 0; m < 8; ++m) {
      float sc[4];
#pragma unroll
      for (int r = 0; r < 4; ++r) {
        float dv = lb[row0 + m * 16 + r];
        sc[r] = (dv > 0.0f) ? 1.0f / dv : 0.0f;
      }
#pragma unroll
      for (int n = 0; n < 4; ++n)
#pragma unroll
        for (int r = 0; r < 4; ++r)
          Cb[(long)(row0 + m * 16 + r) * ldc + (col0 + n * 16)] =
              acc[m][n][r] * sc[r];
    }
  }
}

// ======================= FALLBACK PATH (R3, proven) ========================

__device__ __forceinline__ void split8(const float* __restrict__ g, s16x8& h,
                                       s16x8& l) {
  f32x4 a = *(const f32x4*)g;
  f32x4 b = *(const f32x4*)(g + 4);
#pragma unroll
  for (int j = 0; j < 8; ++j) {
    float x = (j < 4) ? a[j] : b[j - 4];
    u16 hu = f2b(x);
    h[j] = (short)hu;
    l[j] = (short)f2b(x - b2f(hu));
  }
}

template <int MODE>
__global__ __launch_bounds__(256, 2) void gemm_k(
    const void* __restrict__ Ap, const void* __restrict__ Bp,
    const u16* __restrict__ Blo, void* __restrict__ Cp, u16* __restrict__ C2,
    int K, int ldc, long sA, long sB, long sC, const int* __restrict__ mask,
    int maskStride, const float* __restrict__ lvec, int lvecStride) {
  constexpr bool TRI = (MODE != 2);
  __shared__ s16x8 AsH[512];
  __shared__ s16x8 BsH[512];
  __shared__ s16x8 AsL[TRI ? 512 : 1];
  __shared__ s16x8 BsL[TRI ? 512 : 1];

  const int z = blockIdx.z;
  const int tid = threadIdx.x;
  const int lane = tid & 63;
  const int wid = tid >> 6;

  const f32x4 z4 = {0.f, 0.f, 0.f, 0.f};
  f32x4 acc[4][4];
#pragma unroll
  for (int i = 0; i < 4; ++i)
#pragma unroll
    for (int j = 0; j < 4; ++j) acc[i][j] = z4;

  const int wm = (wid & 1) * 64;
  const int wn = (wid >> 1) * 64;
  const int lrow = lane & 15;
  const int kofs = (lane >> 4) * 8;
  const int srow = tid >> 1;
  const int shalf = (tid & 1) * 16;
  const int lidx = (srow * 32 + shalf) >> 3;

  const u16* AsHu = (const u16*)AsH;
  const u16* BsHu = (const u16*)BsH;
  const u16* AsLu = (const u16*)AsL;
  const u16* BsLu = (const u16*)BsL;

  for (int k0 = 0; k0 < K; k0 += 32) {
    if (MODE == 2) {
      const u16* Ab = (const u16*)Ap + z * sA + (long)blockIdx.y * 128 * K;
      const u16* Bb = (const u16*)Bp + z * sB + (long)blockIdx.x * 128 * K;
      const u16* ga = Ab + (long)srow * K + k0 + shalf;
      const u16* gb = Bb + (long)srow * K + k0 + shalf;
      AsH[lidx] = *(const s16x8*)ga;
      AsH[lidx + 1] = *(const s16x8*)(ga + 8);
      BsH[lidx] = *(const s16x8*)gb;
      BsH[lidx + 1] = *(const s16x8*)(gb + 8);
    } else {
      const float* Ab = (const float*)Ap + z * sA + (long)blockIdx.y * 128 * K;
      const float* ga = Ab + (long)srow * K + k0 + shalf;
      split8(ga, AsH[lidx], AsL[lidx]);
      split8(ga + 8, AsH[lidx + 1], AsL[lidx + 1]);
      if (MODE == 0) {
        const float* Bb = (const float*)Bp + z * sB + (long)blockIdx.x * 128 * K;
        const float* gb = Bb + (long)srow * K + k0 + shalf;
        split8(gb, BsH[lidx], BsL[lidx]);
        split8(gb + 8, BsH[lidx + 1], BsL[lidx + 1]);
      } else {
        const u16* Bh = (const u16*)Bp + z * sB + (long)blockIdx.x * 128 * K;
        const u16* Bl = Blo + z * sB + (long)blockIdx.x * 128 * K;
        const u16* gh = Bh + (long)srow * K + k0 + shalf;
        const u16* gl = Bl + (long)srow * K + k0 + shalf;
        BsH[lidx] = *(const s16x8*)gh;
        BsH[lidx + 1] = *(const s16x8*)(gh + 8);
        BsL[lidx] = *(const s16x8*)gl;
        BsL[lidx + 1] = *(const s16x8*)(gl + 8);
      }
    }
    __syncthreads();
    s16x8 ah[4], bh[4], al[4], bl[4];
#pragma unroll
    for (int t = 0; t < 4; ++t) {
      ah[t] = *(const s16x8*)&AsHu[(wm + t * 16 + lrow) * 32 + kofs];
      bh[t] = *(const s16x8*)&BsHu[(wn + t * 16 + lrow) * 32 + kofs];
      if (TRI) {
        al[t] = *(const s16x8*)&AsLu[(wm + t * 16 + lrow) * 32 + kofs];
        bl[t] = *(const s16x8*)&BsLu[(wn + t * 16 + lrow) * 32 + kofs];
      }
    }
#pragma unroll
    for (int i = 0; i < 4; ++i)
#pragma unroll
      for (int j = 0; j < 4; ++j) {
        acc[i][j] = __builtin_amdgcn_mfma_f32_16x16x32_bf16(ah[i], bh[j],
                                                            acc[i][j], 0, 0, 0);
        if (TRI) {
          acc[i][j] = __builtin_amdgcn_mfma_f32_16x16x32_bf16(
              al[i], bh[j], acc[i][j], 0, 0, 0);
          acc[i][j] = __builtin_amdgcn_mfma_f32_16x16x32_bf16(
              ah[i], bl[j], acc[i][j], 0, 0, 0);
        }
      }
    __syncthreads();
  }

  const int row0 = blockIdx.y * 128 + wm + (lane >> 4) * 4;
  const int col0 = blockIdx.x * 128 + wn + lrow;

  if (MODE == 0) {
    u16* Ch = (u16*)Cp;
#pragma unroll
    for (int i = 0; i < 4; ++i)
#pragma unroll
      for (int j = 0; j < 4; ++j)
#pragma unroll
        for (int r = 0; r < 4; ++r) {
          float v = acc[i][j][r];
          long idx = (long)(row0 + i * 16 + r) * ldc + (col0 + j * 16);
          u16 h = f2b(v);
          Ch[idx] = h;
          C2[idx] = f2b(v - b2f(h));
        }
  } else if (MODE == 1) {
    u16* Cb = (u16*)Cp + z * sC;
    const int* mb = mask + (long)z * maskStride;
    int mcol[4];
#pragma unroll
    for (int j = 0; j < 4; ++j) mcol[j] = mb[col0 + j * 16];
#pragma unroll
    for (int i = 0; i < 4; ++i)
#pragma unroll
      for (int j = 0; j < 4; ++j)
#pragma unroll
        for (int r = 0; r < 4; ++r) {
          float v = acc[i][j][r];
          v = mcol[j] ? __expf(v - 100.0f) : 0.0f;
          Cb[(long)(row0 + i * 16 + r) * ldc + (col0 + j * 16)] = f2b(v);
        }
  } else {
    float* Cb = (float*)Cp + z * sC;
    const float* lb = lvec + (long)z * lvecStride;
    float scale[4][4];
#pragma unroll
    for (int i = 0; i < 4; ++i)
#pragma unroll
      for (int r = 0; r < 4; ++r) {
        float dv = lb[row0 + i * 16 + r];
        scale[i][r] = (dv > 0.0f) ? 1.0f / dv : 0.0f;
      }
#pragma unroll
    for (int i = 0; i < 4; ++i)
#pragma unroll
      for (int j = 0; j < 4; ++j)
#pragma unroll
        for (int r = 0; r < 4; ++r)
          Cb[(long)(row0 + i * 16 + r) * ldc + (col0 + j * 16)] =
              acc[i][j][r] * scale[i][r];
  }
}

// ============================ SHARED SMALL KERNELS =========================

__global__ __launch_bounds__(256) void rowsum_kernel(const u16* __restrict__ E,
                                                     float* __restrict__ l) {
  const int row = blockIdx.x * 4 + (threadIdx.x >> 6);
  const int lane = threadIdx.x & 63;
  const u16* p = E + (size_t)row * S1_;
  float s = 0.f;
#pragma unroll
  for (int j = 0; j < 4; ++j) {
    u16x8 v = *(const u16x8*)(p + (j * 64 + lane) * 8);
#pragma unroll
    for (int k = 0; k < 8; ++k) s += b2f(v[k]);
  }
#pragma unroll
  for (int off = 32; off; off >>= 1) s += __shfl_down(s, off, 64);
  if (lane == 0) l[row] = s;
}

// Gather-transpose: out[b][d][j] = bf16(in[b][sidx[b][j]][d]) for j<cnt,
// 0 for j in [cnt, kr); blocks with s0 >= kr exit (cols >= kr never read).
__global__ __launch_bounds__(256) void transposeC_kernel(
    const float* __restrict__ in, const int* __restrict__ sidx,
    const int* __restrict__ cnt, const int* __restrict__ kr,
    u16* __restrict__ out) {
  __shared__ u16 tile[64][66];
  const int b = blockIdx.z;
  const int s0 = blockIdx.x * 64;
  if (s0 >= kr[b]) return;
  const int cn = cnt[b];
  const int* sx = sidx + (long)b * S1_;
  const float* ib = in + (size_t)b * S1_ * D_;
  u16* ob = out + (size_t)b * D_ * S1_;
  const int d0 = blockIdx.y * 64;
  const int t = threadIdx.x;
  const int tr = t >> 4;
  const int tc = (t & 15) * 4;
#pragma unroll
  for (int i = 0; i < 4; ++i) {
    int row = tr + i * 16;
    int j = s0 + row;
    if (j < cn) {
      f32x4 v = *(const f32x4*)(ib + (size_t)sx[j] * D_ + d0 + tc);
      tile[row][tc + 0] = f2b(v[0]);
      tile[row][tc + 1] = f2b(v[1]);
      tile[row][tc + 2] = f2b(v[2]);
      tile[row][tc + 3] = f2b(v[3]);
    } else {
      tile[row][tc + 0] = 0;
      tile[row][tc + 1] = 0;
      tile[row][tc + 2] = 0;
      tile[row][tc + 3] = 0;
    }
  }
  __syncthreads();
#pragma unroll
  for (int i = 0; i < 4; ++i) {
    int drow = tr + i * 16;
    ushort4 w;
    w.x = tile[tc + 0][drow];
    w.y = tile[tc + 1][drow];
    w.z = tile[tc + 2][drow];
    w.w = tile[tc + 3][drow];
    *(ushort4*)(ob + (size_t)(d0 + drow) * S1_ + s0 + tc) = w;
  }
}

__global__ __launch_bounds__(256) void transpose_kernel(
    const float* __restrict__ in, u16* __restrict__ out) {
  __shared__ u16 tile[64][66];
  const int b = blockIdx.z;
  const float* ib = in + (size_t)b * S1_ * D_;
  u16* ob = out + (size_t)b * D_ * S1_;
  const int s0 = blockIdx.x * 64;
  const int d0 = blockIdx.y * 64;
  const int t = threadIdx.x;
  const int tr = t >> 4;
  const int tc = (t & 15) * 4;
#pragma unroll
  for (int i = 0; i < 4; ++i) {
    int row = tr + i * 16;
    f32x4 v = *(const f32x4*)(ib + (size_t)(s0 + row) * D_ + d0 + tc);
    tile[row][tc + 0] = f2b(v[0]);
    tile[row][tc + 1] = f2b(v[1]);
    tile[row][tc + 2] = f2b(v[2]);
    tile[row][tc + 3] = f2b(v[3]);
  }
  __syncthreads();
#pragma unroll
  for (int i = 0; i < 4; ++i) {
    int drow = tr + i * 16;
    ushort4 w;
    w.x = tile[tc + 0][drow];
    w.y = tile[tc + 1][drow];
    w.z = tile[tc + 2][drow];
    w.w = tile[tc + 3][drow];
    *(ushort4*)(ob + (size_t)(d0 + drow) * S1_ + s0 + tc) = w;
  }
}

// ============================ LAUNCH ========================================

extern "C" void kernel_launch(void* const* d_in, const int* in_sizes, int n_in,
                              void* d_out, int out_size, void* d_ws,
                              size_t ws_size, hipStream_t stream) {
  const float* in1 = (const float*)d_in[0];
  const float* in2 = (const float*)d_in[1];
  const int* mask = (const int*)d_in[2];
  const float* W = (const float*)d_in[3];
  float* out = (float*)d_out;
  char* ws = (char*)d_ws;
  const size_t MB = 1024 * 1024;
  const size_t KB = 1024;
  dim3 blk(256);
  dim3 blk512(512);

  const size_t FULL_WS = 196 * MB + 64 * 1024;
  if (ws_size >= FULL_WS) {
    // Layout: [0,32) in1_h -> in1TC(bf16) after GEMM1 ; [32,64) in2_h ;
    // [64,66) W_h ; [66,130) ET (bf16, compact cols) ; [130,162) out1C_h ;
    // [162,194) out1C_l ; 194MB: lv(64KB) ; +64KB: sidx(64KB) ; +128KB: cnt,kr.
    u16* in1_h = (u16*)(ws + 0);
    u16* in2_h = (u16*)(ws + 32 * MB);
    u16* W_h = (u16*)(ws + 64 * MB);
    u16* ET = (u16*)(ws + 66 * MB);
    u16* out1C_h = (u16*)(ws + 130 * MB);
    u16* out1C_l = (u16*)(ws + 162 * MB);
    float* lv = (float*)(ws + 194 * MB);
    int* sidx = (int*)(ws + 194 * MB + 64 * KB);
    int* cnt = (int*)(ws + 194 * MB + 128 * KB);
    int* kr = cnt + 8;
    u16* in1TC = (u16*)(ws + 0);  // reuse in1_h region after GEMM1

    split_h_kernel<<<dim3(16384), blk, 0, stream>>>(in1, in1_h,
                                                    B_ * S1_ * D_ / 4);
    split_h_kernel<<<dim3(16384), blk, 0, stream>>>(in2, in2_h,
                                                    B_ * S2_ * D_ / 4);
    split_h_kernel<<<dim3(1024), blk, 0, stream>>>(W, W_h, D_ * D_ / 4);
    // Zero lv (16K floats) + sidx (16K ints), contiguous 32K words.
    zero_kernel<<<dim3(128), blk, 0, stream>>>(lv, 32768);
    compact_kernel<<<dim3(B_), blk, 0, stream>>>(mask, sidx, cnt, kr);

    // GEMM1 (compacted M): out1C[b][j] = in1[b][sidx[j]] @ W^T, fp16 1-term,
    // per batch M=2048(pad) N=1024 K=1024; early-exit by kr[b].
    gemm8<1, 0, true, true, false><<<dim3(4, 8, B_), blk512, 0, stream>>>(
        in1_h, in1_h, in1_h, W_h, W_h, W_h, out1C_h, out1C_l, D_, D_, D_, D_,
        (long)S1_ * D_, 0L, (long)S1_ * D_, sidx, S1_, cnt, kr, nullptr, 0);

    // Gather-transpose: in1TC[b][d][j] = bf16(in1[b][sidx[j]][d]); zero pad.
    // (After GEMM1: overwrites in1_h region.)
    transposeC_kernel<<<dim3(S1_ / 64, D_ / 64, B_), blk, 0, stream>>>(
        in1, sidx, cnt, kr, in1TC);

    // GEMM2 (compact N): ET[t,j] = exp(<in2[t], out1C[j]> - 100) for j<cnt,
    // else 0; fp16 2-term (B segs {h,l}); fused row-sum into lv; early-exit
    // by kr[b].
    gemm8<2, 1, true, false, false><<<dim3(8, 8, B_), blk512, 0, stream>>>(
        in2_h, in2_h, in2_h, out1C_h, out1C_l, out1C_l, ET, nullptr, D_, D_,
        D_, S1_, (long)S2_ * D_, (long)S1_ * D_, (long)S2_ * S1_, nullptr, 0,
        cnt, kr, lv, S2_);

    // GEMM3 (compact K = kr[b]): satt = (ET @ in1TC^T) / l, bf16 1-term,
    // per batch M=2048 N=1024.
    gemm8<1, 2, false, false, true><<<dim3(4, 8, B_), blk512, 0, stream>>>(
        ET, ET, ET, in1TC, in1TC, in1TC, out, nullptr, 0, S1_, S1_, D_,
        (long)S2_ * S1_, (long)D_ * S1_, (long)S2_ * D_, nullptr, 0, cnt, kr,
        lv, S2_);
  } else {
    // R3-proven fallback (in-kernel split), 128MB + 64KB.
    u16* out1_hi = (u16*)ws;
    u16* out1_lo = (u16*)(ws + 32 * MB);
    u16* ET = (u16*)(ws + 64 * MB);
    float* lv = (float*)(ws + 128 * MB);
    u16* in1T = out1_hi;

    gemm_k<0><<<dim3(8, 128, 1), blk, 0, stream>>>(
        in1, W, nullptr, out1_hi, out1_lo, D_, D_, 0, 0, 0, nullptr, 0,
        nullptr, 0);
    gemm_k<1><<<dim3(16, 16, B_), blk, 0, stream>>>(
        in2, out1_hi, out1_lo, ET, nullptr, D_, S1_, (long)S2_ * D_,
        (long)S1_ * D_, (long)S2_ * S1_, mask, S1_, nullptr, 0);
    rowsum_kernel<<<dim3(B_ * S2_ / 4), blk, 0, stream>>>(ET, lv);
    transpose_kernel<<<dim3(S1_ / 64, D_ / 64, B_), blk, 0, stream>>>(in1, in1T);
    gemm_k<2><<<dim3(8, 16, B_), blk, 0, stream>>>(
        ET, in1T, nullptr, out, nullptr, S1_, D_, (long)S2_ * S1_,
        (long)D_ * S1_, (long)S2_ * D_, nullptr, 0, lv, S2_);
  }
}